// Round 1
// baseline (54.297 us; speedup 1.0000x reference)
//
#include <hip/hip_runtime.h>

// ---- problem constants ----
#define BATCH 65536
#define KREAL 784          // 28*28 image = GEMM-K (conv folded into Weff)
#define KPAD  832          // 13 * 64
#define BK    64           // K-chunk staged per iteration
#define NCHUNK 13
#define HID   128
#define NOUT  10
#define BM    64           // rows per block

using f32x4  = __attribute__((ext_vector_type(4))) float;
using short8 = __attribute__((ext_vector_type(8))) short;   // 8 bf16 (4 VGPRs)
using f4     = __attribute__((ext_vector_type(4))) float;

__device__ inline unsigned short f2bf(float f) {
    union { float f; unsigned int u; } c; c.f = f;
    unsigned int u = c.u;
    u += 0x7fffu + ((u >> 16) & 1u);          // round-to-nearest-even
    return (unsigned short)(u >> 16);
}

// ---------------------------------------------------------------------------
// Prep: Weff[128][832] = conv folded into w1 (bf16, zero-padded K>=784),
//       w2p[16][128]  = w2 zero-padded to 16 output cols (bf16).
// ---------------------------------------------------------------------------
__global__ void prep_kernel(const float* __restrict__ conv_w,
                            const float* __restrict__ w1,
                            const float* __restrict__ w2,
                            unsigned short* __restrict__ weff,
                            unsigned short* __restrict__ w2p)
{
    int idx = blockIdx.x * 256 + threadIdx.x;
    if (idx < HID * KPAD) {
        int o = idx / KPAD;
        int p = idx - o * KPAD;
        float acc = 0.f;
        if (p < KREAL) {
            int r = p / 28, c = p - r * 28;
            #pragma unroll
            for (int di = 0; di < 3; ++di) {
                int i = r - di;
                if (i >= 0 && i < 26) {
                    #pragma unroll
                    for (int dj = 0; dj < 3; ++dj) {
                        int j = c - dj;
                        if (j >= 0 && j < 26)
                            acc = fmaf(w1[o * 676 + i * 26 + j], conv_w[di * 3 + dj], acc);
                    }
                }
            }
        }
        weff[idx] = f2bf(acc);
    } else {
        int k = idx - HID * KPAD;
        if (k < 16 * HID) {
            int o = k >> 7, c = k & 127;
            float v = (o < NOUT) ? w2[o * HID + c] : 0.f;
            w2p[k] = f2bf(v);
        }
    }
}

// ---------------------------------------------------------------------------
// Fused GEMM1 (x @ Weff^T + b1, ReLU)  ->  GEMM2 (h @ w2p^T + b2)
// BM=64 rows/block, 4 waves, each wave owns 16 rows x 128 cols.
// LDS tiles swizzled: 16B chunk g of row r stored at position g ^ (r&7)
// (row stride 128B -> bank-balanced ds_read_b128 / ds_write_b128).
// ---------------------------------------------------------------------------
__global__ void fused_mlp_kernel(const float* __restrict__ x,
                                 const float* __restrict__ b1,
                                 const float* __restrict__ b2,
                                 const unsigned short* __restrict__ weff,
                                 const unsigned short* __restrict__ w2p,
                                 float* __restrict__ out)
{
    __shared__ __align__(16) unsigned short ldsA[BM * BK];    // 8 KB (swizzled)
    __shared__ __align__(16) unsigned short ldsB[HID * BK];   // 16 KB (swizzled)
    __shared__ __align__(16) unsigned short ldsH[BM * HID];   // 16 KB (plain)

    const int tid  = threadIdx.x;
    const int wv   = tid >> 6;
    const int lane = tid & 63;
    const int lo   = lane & 15;
    const int hi   = lane >> 4;
    const int row0 = blockIdx.x * BM;
    const int wr0  = wv * 16;                  // wave's 16-row subtile

    f32x4 acc[8];
    #pragma unroll
    for (int t = 0; t < 8; ++t) acc[t] = (f32x4){0.f, 0.f, 0.f, 0.f};

    // staging roles
    const int rA = tid >> 2;                   // 0..63  (A row)
    const int qA = tid & 3;                    // 16-float group within BK
    const float* xrow = x + (long)(row0 + rA) * KREAL;
    const int rB = tid >> 1;                   // 0..127 (B row = output col)
    const int hB = tid & 1;                    // 32-col half
    const f4 fz = {0.f, 0.f, 0.f, 0.f};

    for (int ic = 0; ic < NCHUNK; ++ic) {
        const int kbase = ic * BK;
        __syncthreads();                       // previous chunk's compute done

        // ---- stage A: x fp32 -> bf16, swizzled ----
        {
            f4 v[4];
            #pragma unroll
            for (int m = 0; m < 4; ++m) {
                int col = kbase + qA * 16 + m * 4;
                v[m] = (col < KREAL) ? *(const f4*)(xrow + col) : fz;
            }
            short8 c0, c1;
            #pragma unroll
            for (int e = 0; e < 4; ++e) {
                c0[e]     = (short)f2bf(v[0][e]);
                c0[4 + e] = (short)f2bf(v[1][e]);
                c1[e]     = (short)f2bf(v[2][e]);
                c1[4 + e] = (short)f2bf(v[3][e]);
            }
            const int sw = rA & 7;
            *(short8*)&ldsA[rA * BK + (((2 * qA)     ^ sw) << 3)] = c0;
            *(short8*)&ldsA[rA * BK + (((2 * qA + 1) ^ sw) << 3)] = c1;
        }
        // ---- stage B: Weff chunk, swizzled ----
        {
            const unsigned short* srcB = weff + rB * KPAD + kbase + hB * 32;
            const int sw = rB & 7;
            #pragma unroll
            for (int m = 0; m < 4; ++m) {
                short8 vb = *(const short8*)(srcB + m * 8);
                int g = hB * 4 + m;
                *(short8*)&ldsB[rB * BK + ((g ^ sw) << 3)] = vb;
            }
        }
        __syncthreads();                       // tiles visible

        // ---- compute: 2 k-sub-steps x 8 n-tiles ----
        #pragma unroll
        for (int kk = 0; kk < 2; ++kk) {
            const int ra = wr0 + lo;                   // A row for this lane
            const int gA = kk * 4 + hi;                // 16B chunk index
            short8 afrag = *(const short8*)&ldsA[ra * BK + ((gA ^ (ra & 7)) << 3)];
            #pragma unroll
            for (int t = 0; t < 8; ++t) {
                const int ob = t * 16 + lo;            // B row (output col)
                short8 bfrag = *(const short8*)&ldsB[ob * BK + ((gA ^ (ob & 7)) << 3)];
                acc[t] = __builtin_amdgcn_mfma_f32_16x16x32_bf16(afrag, bfrag, acc[t], 0, 0, 0);
            }
        }
    }

    // ---- FC1 epilogue: +b1, ReLU, h -> LDS as bf16 ----
    // C/D layout: col = lane&15 (within n-tile), row = (lane>>4)*4 + reg
    #pragma unroll
    for (int t = 0; t < 8; ++t) {
        float bias = b1[t * 16 + lo];
        #pragma unroll
        for (int j = 0; j < 4; ++j) {
            float hv = acc[t][j] + bias;
            hv = hv > 0.f ? hv : 0.f;
            int rloc = wr0 + hi * 4 + j;
            ldsH[rloc * HID + t * 16 + lo] = f2bf(hv);
        }
    }
    __syncthreads();

    // ---- FC2: h[16x128] @ w2p^T[128x16] per wave, 4 MFMAs ----
    f32x4 acc2 = (f32x4){0.f, 0.f, 0.f, 0.f};
    #pragma unroll
    for (int kk = 0; kk < 4; ++kk) {
        short8 ha = *(const short8*)&ldsH[(wr0 + lo) * HID + kk * 32 + hi * 8];
        short8 wb = *(const short8*)(w2p + lo * HID + kk * 32 + hi * 8);
        acc2 = __builtin_amdgcn_mfma_f32_16x16x32_bf16(ha, wb, acc2, 0, 0, 0);
    }
    if (lo < NOUT) {
        float bb = b2[lo];
        #pragma unroll
        for (int j = 0; j < 4; ++j) {
            int grow = row0 + wr0 + hi * 4 + j;
            out[grow * NOUT + lo] = acc2[j] + bb;
        }
    }
}

// ---------------------------------------------------------------------------
extern "C" void kernel_launch(void* const* d_in, const int* in_sizes, int n_in,
                              void* d_out, int out_size, void* d_ws, size_t ws_size,
                              hipStream_t stream)
{
    const float* x      = (const float*)d_in[0];
    const float* conv_w = (const float*)d_in[1];
    const float* w1     = (const float*)d_in[2];
    const float* b1     = (const float*)d_in[3];
    const float* w2     = (const float*)d_in[4];
    const float* b2     = (const float*)d_in[5];
    float* out = (float*)d_out;

    unsigned short* weff = (unsigned short*)d_ws;            // 128*832 bf16
    unsigned short* w2p  = weff + HID * KPAD;                // 16*128 bf16

    const int prep_total = HID * KPAD + 16 * HID;            // 108544
    prep_kernel<<<(prep_total + 255) / 256, 256, 0, stream>>>(conv_w, w1, w2, weff, w2p);
    fused_mlp_kernel<<<BATCH / BM, 256, 0, stream>>>(x, b1, b2, weff, w2p, out);
}

// Round 2
// 46.018 us; speedup vs baseline: 1.1799x; 1.1799x over previous
//
#include <hip/hip_runtime.h>
#include <hip/hip_bf16.h>

// ---- problem constants ----
#define BATCH  65536
#define KREAL  784          // 28*28 = GEMM-K (conv folded into Weff)
#define BK     64
#define NCHUNK 13
#define KPAD   (NCHUNK*BK)  // 832
#define HID    128
#define NOUT   10
#define BM     128          // rows per block
#define NTHR   512          // 8 waves

using f32x4  = __attribute__((ext_vector_type(4))) float;
using short8 = __attribute__((ext_vector_type(8))) short;   // 8 bf16
using f4     = __attribute__((ext_vector_type(4))) float;

__device__ inline short f2b(float f) {
    union { __hip_bfloat16 h; short s; } u;
    u.h = __float2bfloat16(f);               // hardware RNE cvt (v_cvt_pk_bf16_f32)
    return u.s;
}

// global -> LDS direct copy, 16 B per lane. gp: per-lane global addr,
// lp: wave-uniform LDS base (HW writes base + lane*16).
#define GLDS16(gp, lp) \
    __builtin_amdgcn_global_load_lds((const __attribute__((address_space(1))) void*)(gp), \
                                     (__attribute__((address_space(3))) void*)(lp), 16, 0, 0)

// ---------------------------------------------------------------------------
// Prep: weff_sw = conv folded into w1, bf16, CHUNK-MAJOR and PRE-SWIZZLED:
//   weff_sw[ic][r][gsw][e]  holds logical Weff[r][ic*64 + (gsw^(r&7))*8 + e]
// so a linear 16 KB copy of chunk ic yields the swizzled LDS B-tile.
// w2p[16][128] = w2 zero-padded (bf16).
// ---------------------------------------------------------------------------
__global__ void prep_kernel(const float* __restrict__ conv_w,
                            const float* __restrict__ w1,
                            const float* __restrict__ w2,
                            unsigned short* __restrict__ weff_sw,
                            unsigned short* __restrict__ w2p)
{
    const int NW = NCHUNK * HID * BK;        // 106496
    int idx = blockIdx.x * 256 + threadIdx.x;
    if (idx < NW) {
        int ic  = idx >> 13;                 // /(128*64)
        int rem = idx & 8191;
        int r   = rem >> 6;
        int cc  = rem & 63;
        int g   = (cc >> 3) ^ (r & 7);       // logical 8-elem group
        int k   = ic * BK + g * 8 + (cc & 7);
        float acc = 0.f;
        if (k < KREAL) {
            int rr = k / 28, c = k - rr * 28;
            #pragma unroll
            for (int di = 0; di < 3; ++di) {
                int i = rr - di;
                if (i >= 0 && i < 26) {
                    #pragma unroll
                    for (int dj = 0; dj < 3; ++dj) {
                        int j = c - dj;
                        if (j >= 0 && j < 26)
                            acc = fmaf(w1[r * 676 + i * 26 + j], conv_w[di * 3 + dj], acc);
                    }
                }
            }
        }
        weff_sw[idx] = (unsigned short)f2b(acc);
    } else {
        int k = idx - NW;
        if (k < 16 * HID) {
            int o = k >> 7, c = k & 127;
            w2p[k] = (unsigned short)f2b((o < NOUT) ? w2[o * HID + c] : 0.f);
        }
    }
}

// ---------------------------------------------------------------------------
// Fused: relu(x @ Weff^T + b1) @ w2p^T + b2
// 512 thr (8 waves), BM=128: wave wv owns rows [wv*16, wv*16+16) x 128 cols.
// LDS 32 KB: ldsA[128][64] + ldsB[128][64] (both 16B-group XOR-swizzled);
// ldsH[128][128] aliases them after the K-loop.
// ---------------------------------------------------------------------------
__global__ __launch_bounds__(NTHR, 4)
void fused_mlp_kernel(const float* __restrict__ x,
                      const float* __restrict__ b1,
                      const float* __restrict__ b2,
                      const unsigned short* __restrict__ weff_sw,
                      const unsigned short* __restrict__ w2p,
                      float* __restrict__ out)
{
    __shared__ __align__(16) unsigned short smem[16384];   // 32 KB
    unsigned short* ldsA = smem;            // [128][64] swizzled
    unsigned short* ldsB = smem + 8192;     // [128][64] swizzled (linear copy of weff_sw chunk)
    unsigned short* ldsH = smem;            // [128][128] swizzled, aliased

    const int tid  = threadIdx.x;
    const int wv   = tid >> 6;
    const int lane = tid & 63;
    const int lo   = lane & 15;
    const int hi   = lane >> 4;
    const int row0 = blockIdx.x * BM;
    const int wr0  = wv * 16;

    f32x4 acc[8];
    #pragma unroll
    for (int t = 0; t < 8; ++t) acc[t] = (f32x4){0.f, 0.f, 0.f, 0.f};

    // A-staging role: thread stages 16 floats of one row
    const int rA  = tid >> 2;               // 0..127
    const int qA  = tid & 3;                // 16-col group within BK
    const int swA = rA & 7;
    const float* xrow = x + (long)(row0 + rA) * KREAL;
    const f4 fz = {0.f, 0.f, 0.f, 0.f};

    for (int ic = 0; ic < NCHUNK; ++ic) {
        const int kbase = ic * BK;
        __syncthreads();                    // previous chunk's reads done

        // ---- stage B: linear 16 KB global_load_lds (pre-swizzled source) ----
        {
            const char* src = (const char*)(weff_sw + ic * (HID * BK));
            int o0 = wv * 1024 + lane * 16;             // bytes [0, 8K)
            GLDS16(src + o0,        (char*)ldsB + wv * 1024);
            GLDS16(src + o0 + 8192, (char*)ldsB + wv * 1024 + 8192);
        }
        // ---- stage A: x fp32 -> bf16, swizzled ds_write_b128 x2 ----
        {
            f4 v[4];
            #pragma unroll
            for (int m = 0; m < 4; ++m) {
                int col = kbase + qA * 16 + m * 4;
                v[m] = (col < KREAL) ? *(const f4*)(xrow + col) : fz;
            }
            short8 c0, c1;
            #pragma unroll
            for (int e = 0; e < 4; ++e) {
                c0[e]     = f2b(v[0][e]);
                c0[4 + e] = f2b(v[1][e]);
                c1[e]     = f2b(v[2][e]);
                c1[4 + e] = f2b(v[3][e]);
            }
            *(short8*)&ldsA[rA * BK + (((2 * qA)     ^ swA) << 3)] = c0;
            *(short8*)&ldsA[rA * BK + (((2 * qA + 1) ^ swA) << 3)] = c1;
        }
        __syncthreads();                    // tiles visible

        // ---- compute: 2 k-substeps x 8 n-tiles ----
        #pragma unroll
        for (int kk = 0; kk < 2; ++kk) {
            const int ra = wr0 + lo;
            const int gA = kk * 4 + hi;
            short8 afrag = *(const short8*)&ldsA[ra * BK + ((gA ^ (ra & 7)) << 3)];
            #pragma unroll
            for (int t = 0; t < 8; ++t) {
                const int ob = t * 16 + lo;
                short8 bfrag = *(const short8*)&ldsB[ob * BK + ((gA ^ (ob & 7)) << 3)];
                acc[t] = __builtin_amdgcn_mfma_f32_16x16x32_bf16(afrag, bfrag, acc[t], 0, 0, 0);
            }
        }
    }

    __syncthreads();                        // K-loop done; smem reuse (ldsH) safe

    // ---- FC1 epilogue: +b1, ReLU, h -> swizzled ldsH (own-wave rows only) ----
    // C/D layout: col = lane&15, row = (lane>>4)*4 + reg
    #pragma unroll
    for (int t = 0; t < 8; ++t) {
        float bias = b1[t * 16 + lo];
        #pragma unroll
        for (int j = 0; j < 4; ++j) {
            float hv = acc[t][j] + bias;
            hv = hv > 0.f ? hv : 0.f;
            int rloc = wr0 + hi * 4 + j;
            int col  = t * 16 + lo;
            int g    = col >> 3, e = col & 7;
            ldsH[rloc * HID + ((g ^ (rloc & 7)) << 3) + e] = (unsigned short)f2b(hv);
        }
    }
    // wave reads only its own writes -> lgkmcnt (compiler) suffices, no barrier

    // ---- FC2: h[16x128] @ w2p^T[128x16] per wave, 4 MFMAs ----
    f32x4 acc2 = (f32x4){0.f, 0.f, 0.f, 0.f};
    #pragma unroll
    for (int kk = 0; kk < 4; ++kk) {
        int r = wr0 + lo;
        int g = kk * 4 + hi;
        short8 ha = *(const short8*)&ldsH[r * HID + ((g ^ (r & 7)) << 3)];
        short8 wb = *(const short8*)(w2p + lo * HID + kk * 32 + hi * 8);
        acc2 = __builtin_amdgcn_mfma_f32_16x16x32_bf16(ha, wb, acc2, 0, 0, 0);
    }
    if (lo < NOUT) {
        float bb = b2[lo];
        #pragma unroll
        for (int j = 0; j < 4; ++j) {
            int grow = row0 + wr0 + hi * 4 + j;
            out[grow * NOUT + lo] = acc2[j] + bb;
        }
    }
}

// ---------------------------------------------------------------------------
extern "C" void kernel_launch(void* const* d_in, const int* in_sizes, int n_in,
                              void* d_out, int out_size, void* d_ws, size_t ws_size,
                              hipStream_t stream)
{
    const float* x      = (const float*)d_in[0];
    const float* conv_w = (const float*)d_in[1];
    const float* w1     = (const float*)d_in[2];
    const float* b1     = (const float*)d_in[3];
    const float* w2     = (const float*)d_in[4];
    const float* b2     = (const float*)d_in[5];
    float* out = (float*)d_out;

    unsigned short* weff_sw = (unsigned short*)d_ws;         // 13*128*64 bf16
    unsigned short* w2p     = weff_sw + NCHUNK * HID * BK;   // 16*128 bf16

    const int prep_total = NCHUNK * HID * BK + 16 * HID;     // 108544
    prep_kernel<<<(prep_total + 255) / 256, 256, 0, stream>>>(conv_w, w1, w2, weff_sw, w2p);
    fused_mlp_kernel<<<BATCH / BM, NTHR, 0, stream>>>(x, b1, b2, weff_sw, w2p, out);
}